// Round 9
// baseline (135.013 us; speedup 1.0000x reference)
//
#include <hip/hip_runtime.h>
#include <math.h>

typedef __attribute__((ext_vector_type(8))) short short8;
typedef __attribute__((ext_vector_type(4))) float f32x4;

#define B_  8
#define S_  512
#define D_  1024
#define H_  16
#define DH_ 64

__device__ __forceinline__ unsigned short f2bf(float f) {
    unsigned int u = __float_as_uint(f);
    u += 0x7FFFu + ((u >> 16) & 1u);      // round-to-nearest-even
    return (unsigned short)(u >> 16);
}
__device__ __forceinline__ float bf2f(unsigned short u) {
    return __uint_as_float(((unsigned int)u) << 16);
}
__device__ __forceinline__ void gload_lds16(const void* g, void* l) {
    __builtin_amdgcn_global_load_lds(
        (const __attribute__((address_space(1))) unsigned int*)g,
        (__attribute__((address_space(3))) unsigned int*)l, 16, 0, 0);
}

// ---------------------------------------------------------------------------
// f32 -> bf16 converter for the 6 GEMM operands (query,key,value,Wq,Wk,Wv).
// Abf = [3][4096][1024] bf16 in the prob output region (scratch until attn);
// Wbf = [3][1024][1024] bf16 in ws.
// ---------------------------------------------------------------------------
__global__ __launch_bounds__(256) void conv_bf16(
    const float* __restrict__ q, const float* __restrict__ k, const float* __restrict__ v,
    const float* __restrict__ wq, const float* __restrict__ wk, const float* __restrict__ wv,
    unsigned short* __restrict__ Abf, unsigned short* __restrict__ Wbf)
{
    const size_t NA = 1048576;   // float4s per A tensor (4M elts / 4)
    const size_t NW = 262144;    // float4s per W tensor
    const size_t total = 3*NA + 3*NW;
    for (size_t i4 = (size_t)blockIdx.x*blockDim.x + threadIdx.x; i4 < total;
         i4 += (size_t)gridDim.x*blockDim.x) {
        const float* s; unsigned short* d; size_t off;
        if (i4 < 3*NA) {
            const int z = (int)(i4 / NA);
            s = (z == 0) ? q : (z == 1) ? k : v;
            off = i4 - (size_t)z*NA;
            d = Abf + (size_t)z*NA*4;
        } else {
            const size_t j = i4 - 3*NA;
            const int z = (int)(j / NW);
            s = (z == 0) ? wq : (z == 1) ? wk : wv;
            off = j - (size_t)z*NW;
            d = Wbf + (size_t)z*NW*4;
        }
        const float4 f = ((const float4*)s)[off];
        ushort4 u; u.x = f2bf(f.x); u.y = f2bf(f.y); u.z = f2bf(f.z); u.w = f2bf(f.w);
        ((ushort4*)d)[off] = u;
    }
}

// ---------------------------------------------------------------------------
// QKV projection GEMM, m97 structure (R4 known-good: ~38 us): 128x128 tile,
// BK=64, 4 waves, global_load_lds(16B) staging into XOR-swizzled LDS content
// (linear LDS dest + pre-swizzled global source + swizzled ds_read).
// z==0/1: q/k in head layout [bh][s][dh] (0.125 folded into q).
// z==2:   V directly transposed [bh][dh][s] (ushort4 stores).
// 1D grid 768, XCD-bijective swizzle (768%8==0).
// ---------------------------------------------------------------------------
__global__ __launch_bounds__(256) void qkv_gemm(
    const unsigned short* __restrict__ Abf, const unsigned short* __restrict__ Wbf,
    const float* __restrict__ bq, const float* __restrict__ bk, const float* __restrict__ bv,
    unsigned short* __restrict__ qw, unsigned short* __restrict__ kw,
    unsigned short* __restrict__ vtw)
{
    __shared__ unsigned short As[128][64];   // 16 KB, content XOR-swizzled
    __shared__ unsigned short Bs[128][64];

    const int bid = blockIdx.x;
    const int wid = (bid & 7) * 96 + (bid >> 3);
    const int z   = wid >> 8;            // tensor
    const int rem = wid & 255;
    const int bm  = (rem >> 3) * 128;    // m-block
    const int bn  = (rem & 7) * 128;     // n-block

    const unsigned short* A = Abf + (size_t)z * 4194304;
    const unsigned short* W = Wbf + (size_t)z * 1048576;
    const float* bias = (z == 0) ? bq : (z == 1) ? bk : bv;
    const float scale = (z == 0) ? 0.125f : 1.0f;   // fold 1/sqrt(dh) into q

    const int t = threadIdx.x, w = t >> 6, l = t & 63, lr = l & 15, lg = l >> 4;
    const int wr = (w >> 1) * 64, wc = (w & 1) * 64;

    const int srow = t >> 3;                       // 0..31
    const int scol = 8 * ((t & 7) ^ (srow & 7));   // pre-swizzled source col
    const unsigned short* Ast = A + (size_t)(bm + srow) * 1024 + scol;
    const unsigned short* Wst = W + (size_t)(bn + srow) * 1024 + scol;
    char* AsB = (char*)As; char* BsB = (char*)Bs;

    f32x4 acc[4][4] = {};
    for (int k0 = 0; k0 < 1024; k0 += 64) {
        __syncthreads();                           // prev tile fully consumed
        #pragma unroll
        for (int j = 0; j < 4; j++) {
            gload_lds16(Ast + (size_t)(32*j)*1024 + k0, AsB + 4096*j + t*16);
            gload_lds16(Wst + (size_t)(32*j)*1024 + k0, BsB + 4096*j + t*16);
        }
        __syncthreads();                           // drains vmcnt -> LDS valid
        #pragma unroll
        for (int s = 0; s < 2; s++) {
            short8 af[4], bf4[4];
            #pragma unroll
            for (int i = 0; i < 4; i++) {
                const int row = wr + 16*i + lr;
                af[i] = *(const short8*)(AsB + row*128 + (((4*s + lg) ^ (row & 7)) << 4));
            }
            #pragma unroll
            for (int j = 0; j < 4; j++) {
                const int row = wc + 16*j + lr;
                bf4[j] = *(const short8*)(BsB + row*128 + (((4*s + lg) ^ (row & 7)) << 4));
            }
            #pragma unroll
            for (int i = 0; i < 4; i++)
                #pragma unroll
                for (int j = 0; j < 4; j++)
                    acc[i][j] = __builtin_amdgcn_mfma_f32_16x16x32_bf16(af[i], bf4[j], acc[i][j], 0, 0, 0);
        }
    }

    if (z < 2) {
        unsigned short* outp = (z == 0) ? qw : kw;
        #pragma unroll
        for (int j = 0; j < 4; j++) {
            const int n = bn + wc + 16*j + lr;
            const float bvx = bias[n];
            const int h = n >> 6, dh = n & 63;
            #pragma unroll
            for (int i = 0; i < 4; i++)
                #pragma unroll
                for (int r = 0; r < 4; r++) {
                    const int m = bm + wr + 16*i + 4*lg + r;   // D row = 4*(l>>4)+reg
                    const int bb = m >> 9, s = m & 511;
                    outp[(((size_t)(bb*H_ + h))*S_ + s)*DH_ + dh] = f2bf((acc[i][j][r] + bvx) * scale);
                }
        }
    } else {
        // V: write transposed [bh][dh][s]; r -> consecutive s -> ushort4
        #pragma unroll
        for (int j = 0; j < 4; j++) {
            const int n = bn + wc + 16*j + lr;
            const float bvx = bias[n];
            const int h = n >> 6, dh = n & 63;
            #pragma unroll
            for (int i = 0; i < 4; i++) {
                const int m0 = bm + wr + 16*i + 4*lg;          // s0 = m0&511 (4-aligned)
                const int bb = m0 >> 9, s0 = m0 & 511;
                ushort4 u;
                u.x = f2bf(acc[i][j][0] + bvx); u.y = f2bf(acc[i][j][1] + bvx);
                u.z = f2bf(acc[i][j][2] + bvx); u.w = f2bf(acc[i][j][3] + bvx);
                *(ushort4*)&vtw[(((size_t)(bb*H_ + h))*DH_ + dh)*S_ + s0] = u;
            }
        }
    }
}

// ---------------------------------------------------------------------------
// E[b][q][k] = c_t*time_attn + c_r*rel_attn  (head-independent), bf16 out.
// R1 = sigmoid(gf-cf)+gf is constant along k -> cancels in softmax.
// ---------------------------------------------------------------------------
__global__ __launch_bounds__(256) void e_kernel(
    const float* __restrict__ rel, const float* __restrict__ tsp,
    const float* __restrict__ pl1, const float* __restrict__ pl2,
    unsigned short* __restrict__ E)
{
    const int t = threadIdx.x, w = t >> 6, l = t & 63;
    const int ridx = blockIdx.x * 4 + w;        // b*S + q
    const int q = ridx & (S_ - 1);
    const float l1 = *pl1, l2 = *pl2;
    const float c_t = (1.f - l1) * l2, c_r = l1;
    const float* tr = tsp + (size_t)ridx * S_;
    const float* rr = rel + (size_t)ridx * S_;

    float tv[8], rv[8]; float st = 0.f, sr = 0.f;
    #pragma unroll
    for (int j = 0; j < 8; j++) {
        const int k = l + 64*j;
        const float rvv = rr[k];
        rv[j] = (rvv != 0.f) ? __expf(rvv) : 0.f;   // exp(-10000)==0 exactly
        sr += rv[j];
        float tvv = 0.f;
        if (k <= q) tvv = __expf(__expf(-fabsf(tr[k])));
        tv[j] = tvv; st += tvv;
    }
    #pragma unroll
    for (int m = 32; m; m >>= 1) { st += __shfl_xor(st, m); sr += __shfl_xor(sr, m); }
    const float ti   = c_t / st;
    const float riv  = (sr > 0.f) ? c_r / sr : 0.f;
    const float runi = (sr > 0.f) ? 0.f : c_r / (float)S_;

    unsigned short* Er = E + (size_t)ridx * S_;
    #pragma unroll
    for (int j = 0; j < 8; j++) {
        const int k = l + 64*j;
        Er[k] = f2bf(tv[j]*ti + rv[j]*riv + runi);
    }
}

// ---------------------------------------------------------------------------
// Fused attention (unchanged). 1D grid 1024; XCD-locality: bid&7 == b.
// prob/out stored NONTEMPORAL to keep K/V/E L2-resident.
// ---------------------------------------------------------------------------
__global__ __launch_bounds__(256) void attn_mfma(
    const unsigned short* __restrict__ qw, const unsigned short* __restrict__ kw,
    const unsigned short* __restrict__ vtw, const unsigned short* __restrict__ E,
    const float* __restrict__ pl1, const float* __restrict__ pl2,
    float* __restrict__ out, float* __restrict__ prob)
{
    __shared__ unsigned short Ps[2][64][72];

    const int t = threadIdx.x, w = t >> 6, l = t & 63, lr = l & 15, lg = l >> 4;
    const int bid = blockIdx.x;
    const int j   = bid >> 3;
    const int bh  = (bid & 7) * 16 + (j & 15);     // b = bid&7, h = j&15
    const int b   = bh >> 4, h = bh & 15;
    const int q0  = (j >> 4) * 64;
    const float l1 = *pl1, l2 = *pl2;
    const float c_p = (1.f - l1) * (1.f - l2);
    const unsigned short* qp = qw + (size_t)bh * (S_ * DH_);
    const unsigned short* kp = kw + (size_t)bh * (S_ * DH_);
    const unsigned short* vt = vtw + (size_t)bh * (DH_ * S_);

    short8 qa[2];
    #pragma unroll
    for (int s = 0; s < 2; s++)
        qa[s] = *(const short8*)&qp[(size_t)(q0 + 16*w + lr)*DH_ + 32*s + 8*lg];

    const int qrb = q0 + 16*w + 4*lg;    // +i = absolute q row for acc elem i

    // ---- pass 1: QK^T, pack scores (bf16 pairs) with causal mask ----
    unsigned int scp[8][4][2];
    #pragma unroll
    for (int ch = 0; ch < 8; ch++) {
        f32x4 a4[4] = {};
        #pragma unroll
        for (int s = 0; s < 2; s++)
            #pragma unroll
            for (int g = 0; g < 4; g++) {
                const short8 kb = *(const short8*)&kp[(size_t)(ch*64 + 16*g + lr)*DH_ + 32*s + 8*lg];
                a4[g] = __builtin_amdgcn_mfma_f32_16x16x32_bf16(qa[s], kb, a4[g], 0, 0, 0);
            }
        #pragma unroll
        for (int g = 0; g < 4; g++) {
            const int k = 64*ch + 16*g + lr;
            const float v0 = (k <= qrb + 0) ? a4[g][0] : -1e30f;
            const float v1 = (k <= qrb + 1) ? a4[g][1] : -1e30f;
            const float v2 = (k <= qrb + 2) ? a4[g][2] : -1e30f;
            const float v3 = (k <= qrb + 3) ? a4[g][3] : -1e30f;
            scp[ch][g][0] = ((unsigned)f2bf(v1) << 16) | f2bf(v0);
            scp[ch][g][1] = ((unsigned)f2bf(v3) << 16) | f2bf(v2);
        }
    }

    // ---- softmax over packed scores ----
    float mx[4] = {-1e30f, -1e30f, -1e30f, -1e30f};
    #pragma unroll
    for (int ch = 0; ch < 8; ch++)
        #pragma unroll
        for (int g = 0; g < 4; g++) {
            const unsigned u0 = scp[ch][g][0], u1 = scp[ch][g][1];
            mx[0] = fmaxf(mx[0], __uint_as_float(u0 << 16));
            mx[1] = fmaxf(mx[1], __uint_as_float(u0 & 0xffff0000u));
            mx[2] = fmaxf(mx[2], __uint_as_float(u1 << 16));
            mx[3] = fmaxf(mx[3], __uint_as_float(u1 & 0xffff0000u));
        }
    #pragma unroll
    for (int i = 0; i < 4; i++)
        #pragma unroll
        for (int m = 8; m; m >>= 1) mx[i] = fmaxf(mx[i], __shfl_xor(mx[i], m));

    float sm[4] = {0.f, 0.f, 0.f, 0.f};
    #pragma unroll
    for (int ch = 0; ch < 8; ch++)
        #pragma unroll
        for (int g = 0; g < 4; g++) {
            const unsigned u0 = scp[ch][g][0], u1 = scp[ch][g][1];
            const float e0 = __expf(__uint_as_float(u0 << 16)          - mx[0]);
            const float e1 = __expf(__uint_as_float(u0 & 0xffff0000u) - mx[1]);
            const float e2 = __expf(__uint_as_float(u1 << 16)          - mx[2]);
            const float e3 = __expf(__uint_as_float(u1 & 0xffff0000u) - mx[3]);
            sm[0] += e0; sm[1] += e1; sm[2] += e2; sm[3] += e3;
            scp[ch][g][0] = ((unsigned)f2bf(e1) << 16) | f2bf(e0);
            scp[ch][g][1] = ((unsigned)f2bf(e3) << 16) | f2bf(e2);
        }
    #pragma unroll
    for (int i = 0; i < 4; i++)
        #pragma unroll
        for (int m = 8; m; m >>= 1) sm[i] += __shfl_xor(sm[i], m);
    float pinv[4];
    #pragma unroll
    for (int i = 0; i < 4; i++) pinv[i] = c_p / sm[i];

    // ---- pass 2: fin -> Ps (dbuf) + nontemporal prob stores; PV MFMA ----
    f32x4 pv[4] = {};
    const unsigned short* Eb = E + ((size_t)b * S_ + qrb) * S_;
    float* pr = prob + ((size_t)bh * S_ + qrb) * S_;
    const int prow = 16*w + 4*lg;

    #pragma unroll
    for (int ch = 0; ch < 8; ch++) {
        const int p = ch & 1;
        #pragma unroll
        for (int g = 0; g < 4; g++) {
            const int kc = 16*g + lr;
            const unsigned u0 = scp[ch][g][0], u1 = scp[ch][g][1];
            const size_t eb = (size_t)(64*ch + kc);
            const float f0 = __uint_as_float(u0 << 16)          * pinv[0] + bf2f(Eb[eb]);
            const float f1 = __uint_as_float(u0 & 0xffff0000u) * pinv[1] + bf2f(Eb[eb + 512]);
            const float f2 = __uint_as_float(u1 << 16)          * pinv[2] + bf2f(Eb[eb + 1024]);
            const float f3 = __uint_as_float(u1 & 0xffff0000u) * pinv[3] + bf2f(Eb[eb + 1536]);
            Ps[p][prow + 0][kc] = f2bf(f0);
            Ps[p][prow + 1][kc] = f2bf(f1);
            Ps[p][prow + 2][kc] = f2bf(f2);
            Ps[p][prow + 3][kc] = f2bf(f3);
            __builtin_nontemporal_store(f0, &pr[eb]);
            __builtin_nontemporal_store(f1, &pr[eb + 512]);
            __builtin_nontemporal_store(f2, &pr[eb + 1024]);
            __builtin_nontemporal_store(f3, &pr[eb + 1536]);
        }
        __syncthreads();
        #pragma unroll
        for (int s = 0; s < 2; s++) {
            const short8 pa = *(const short8*)&Ps[p][16*w + lr][32*s + 8*lg];
            #pragma unroll
            for (int g = 0; g < 4; g++) {
                const short8 vb = *(const short8*)&vt[(size_t)(16*g + lr)*S_ + 64*ch + 32*s + 8*lg];
                pv[g] = __builtin_amdgcn_mfma_f32_16x16x32_bf16(pa, vb, pv[g], 0, 0, 0);
            }
        }
    }

    #pragma unroll
    for (int g = 0; g < 4; g++)
        #pragma unroll
        for (int i = 0; i < 4; i++)
            __builtin_nontemporal_store(pv[g][i],
                &out[((size_t)(b*S_ + qrb + i))*D_ + h*DH_ + 16*g + lr]);
}

// ---------------------------------------------------------------------------
extern "C" void kernel_launch(void* const* d_in, const int* in_sizes, int n_in,
                              void* d_out, int out_size, void* d_ws, size_t ws_size,
                              hipStream_t stream)
{
    const float* query = (const float*)d_in[0];
    const float* key   = (const float*)d_in[1];
    const float* value = (const float*)d_in[2];
    const float* rel   = (const float*)d_in[3];
    const float* tsp   = (const float*)d_in[4];
    const float* l1    = (const float*)d_in[5];
    const float* l2    = (const float*)d_in[6];
    // d_in[7]=mask (causal, recomputed), d_in[8]=encode_pos (unused)
    const float* Wq = (const float*)d_in[9];
    const float* bq = (const float*)d_in[10];
    const float* Wk = (const float*)d_in[11];
    const float* bk = (const float*)d_in[12];
    const float* Wv = (const float*)d_in[13];
    const float* bv = (const float*)d_in[14];
    // Wc/bc/Wg/bg (15..18): R1 constant along softmax axis -> cancels

    float* out  = (float*)d_out;
    float* prob = (float*)d_out + (size_t)B_ * S_ * D_;

    // Abf scratch lives in the prob region (read by gemm before attn writes it)
    unsigned short* Abf = (unsigned short*)prob;           // 3*4M bf16 = 25 MB

    const size_t headN = (size_t)B_ * H_ * S_ * DH_;       // 4,194,304
    unsigned short* Wbf = (unsigned short*)d_ws;           // 3*1M bf16
    unsigned short* qw  = Wbf + 3*1048576;
    unsigned short* kw  = qw + headN;
    unsigned short* vtw = kw + headN;
    unsigned short* Ew  = vtw + headN;                     // B*S*S bf16 = 4.2 MB

    conv_bf16<<<2048, 256, 0, stream>>>(query, key, value, Wq, Wk, Wv, Abf, Wbf);

    qkv_gemm<<<768, 256, 0, stream>>>(Abf, Wbf, bq, bk, bv, qw, kw, vtw);

    e_kernel<<<(B_ * S_) / 4, 256, 0, stream>>>(rel, tsp, l1, l2, Ew);

    attn_mfma<<<1024, 256, 0, stream>>>(qw, kw, vtw, Ew, l1, l2, out, prob);
}